// Round 5
// baseline (160.069 us; speedup 1.0000x reference)
//
#include <hip/hip_runtime.h>
#include <hip/hip_bf16.h>

namespace {

constexpr int B = 4, L = 2048, H = 8, E = 64;
constexpr int RS = H * E;           // 512 floats: row stride in [B,L,H,E]
constexpr float SCALE = 0.125f;     // 1/sqrt(64)
constexpr float THR = 8.0f;         // defer-max threshold (T13)

typedef __attribute__((ext_vector_type(8))) short bf16x8;
typedef __attribute__((ext_vector_type(4))) float f32x4;

__device__ inline unsigned cvt2(float a, float b) {
  __hip_bfloat162 h = __float22bfloat162_rn(make_float2(a, b));  // v_cvt_pk_bf16_f32
  union { __hip_bfloat162 h; unsigned u; } c; c.h = h; return c.u;
}

__device__ inline bf16x8 pack8(float4 a, float4 b) {
  union { bf16x8 v; unsigned u[4]; } r;
  r.u[0] = cvt2(a.x, a.y); r.u[1] = cvt2(a.z, a.w);
  r.u[2] = cvt2(b.x, b.y); r.u[3] = cvt2(b.z, b.w);
  return r.v;
}

// Block = 4 waves handles a COMPLEMENTARY PAIR of q-tiles (j, 127-j) of one
// (b,h): their causal step counts sum to exactly 65, so every block has
// equal work. The pair is split across the 4 waves proportionally
// (split-K chunks per tile), merged via an LDS online-softmax merge.
// Swapped S^T = K·Q^T keeps the softmax row lane-local; P feeds PV's
// A-operand in place. Defer-max: rescale only when a row max grows > THR.
__global__ __launch_bounds__(256)
void fa_mfma(const float* __restrict__ Q, const float* __restrict__ K,
             const float* __restrict__ V, float* __restrict__ O)
{
  const int lane = threadIdx.x & 63;
  const int wv   = threadIdx.x >> 6;
  const int pj   = (int)blockIdx.x >> 5;             // 0..63: tile pair
  const int bh   = (int)blockIdx.x & 31;
  const int b = bh >> 3, h = bh & 7;

  const int ln = lane & 15;                          // row/col within 16-tile
  const int lg = lane >> 4;                          // lane group 0..3
  const int d0 = lg * 4;

  const int tileA = pj, tileB = 127 - pj;
  const int nsA = (16 * tileA + 15) / 32 + 1;        // steps for tile A
  const int nsB = (16 * tileB + 15) / 32 + 1;        // nsA + nsB == 65
  int nwA = (4 * nsA + 32) / 65;                     // proportional waves
  nwA = nwA < 1 ? 1 : (nwA > 3 ? 3 : nwA);
  const int nwB = 4 - nwA;

  int myTile, ns, ci, nc;
  if (wv < nwA) { myTile = tileA; ns = nsA; ci = wv;       nc = nwA; }
  else          { myTile = tileB; ns = nsB; ci = wv - nwA; nc = nwB; }
  const int stepLo = ci * ns / nc;
  const int stepHi = (ci + 1) * ns / nc;

  const size_t base = (size_t)b * L * RS + (size_t)h * E;
  const float* Qb = Q + base;
  const float* Kb = K + base;
  const float* Vb = V + base;
  float*       Ob = O + base;

  const int qrow0 = myTile * 16;

  // Q fragments (B-operand: col = q-row qrow0+ln; k-dims d0.. pattern)
  const float* qp = Qb + (size_t)(qrow0 + ln) * RS;
  const bf16x8 qf0 = pack8(*(const float4*)(qp + d0),      *(const float4*)(qp + d0 + 16));
  const bf16x8 qf1 = pack8(*(const float4*)(qp + d0 + 32), *(const float4*)(qp + d0 + 48));

  f32x4 acc[4];                     // [nt]: dim = ln+16*nt, q-row = d0+r
#pragma unroll
  for (int nt = 0; nt < 4; ++nt) acc[nt] = (f32x4){0.f, 0.f, 0.f, 0.f};
  float m = -1e30f, lsum = 0.f;

  for (int step = stepLo; step < stepHi; ++step) {
    const int kv0 = step * 32;

    // ---- K fragments (A-operand: row = key; two 16-key blocks) ----
    const float* kp0 = Kb + (size_t)(kv0 + ln) * RS;
    const float* kp1 = kp0 + (size_t)16 * RS;
    const bf16x8 kf00 = pack8(*(const float4*)(kp0 + d0),      *(const float4*)(kp0 + d0 + 16));
    const bf16x8 kf01 = pack8(*(const float4*)(kp0 + d0 + 32), *(const float4*)(kp0 + d0 + 48));
    const bf16x8 kf10 = pack8(*(const float4*)(kp1 + d0),      *(const float4*)(kp1 + d0 + 16));
    const bf16x8 kf11 = pack8(*(const float4*)(kp1 + d0 + 32), *(const float4*)(kp1 + d0 + 48));

    f32x4 st0 = (f32x4){0.f,0.f,0.f,0.f}, st1 = st0;
    st0 = __builtin_amdgcn_mfma_f32_16x16x32_bf16(kf00, qf0, st0, 0, 0, 0);
    st0 = __builtin_amdgcn_mfma_f32_16x16x32_bf16(kf01, qf1, st0, 0, 0, 0);
    st1 = __builtin_amdgcn_mfma_f32_16x16x32_bf16(kf10, qf0, st1, 0, 0, 0);
    st1 = __builtin_amdgcn_mfma_f32_16x16x32_bf16(kf11, qf1, st1, 0, 0, 0);

    // ---- per-lane scores: 8 keys of its q-row (qrow0+ln) ----
    float x[8];
#pragma unroll
    for (int r = 0; r < 4; ++r) { x[r] = SCALE * st0[r]; x[4 + r] = SCALE * st1[r]; }

    if (step == ns - 1) {           // only this tile's last step crosses diag
      const int qr = qrow0 + ln;
#pragma unroll
      for (int e = 0; e < 8; ++e) {
        const int key = kv0 + ((e >> 2) << 4) + d0 + (e & 3);
        if (key > qr) x[e] = -1e30f;
      }
    }

    // ---- online softmax with defer-max ----
    float mx = x[0];
#pragma unroll
    for (int e = 1; e < 8; ++e) mx = fmaxf(mx, x[e]);
    mx = fmaxf(mx, __shfl_xor(mx, 16, 64));
    mx = fmaxf(mx, __shfl_xor(mx, 32, 64));

    if (!__all(mx <= m + THR)) {    // rare: row max grew materially
      const float newm = fmaxf(m, mx);
      const float sc = __expf(m - newm);
      lsum *= sc;
      float scr[4];
#pragma unroll
      for (int r = 0; r < 4; ++r) scr[r] = __shfl(sc, d0 + r, 64);
#pragma unroll
      for (int nt = 0; nt < 4; ++nt) {
        acc[nt][0] *= scr[0]; acc[nt][1] *= scr[1];
        acc[nt][2] *= scr[2]; acc[nt][3] *= scr[3];
      }
      m = newm;
    }

    float p[8]; float ps = 0.f;
#pragma unroll
    for (int e = 0; e < 8; ++e) { p[e] = __expf(x[e] - m); ps += p[e]; }
    ps += __shfl_xor(ps, 16, 64);
    ps += __shfl_xor(ps, 32, 64);
    lsum += ps;

    // ---- P fragment (in place: e = key slot, matches A-layout) ----
    union { bf16x8 v; unsigned u[4]; } pf;
#pragma unroll
    for (int e = 0; e < 4; ++e) pf.u[e] = cvt2(p[2*e], p[2*e+1]);

    // ---- V fragments (B-operand: col = dim ln+16nt, k = key) + PV ----
    const float* vp0 = Vb + (size_t)kv0 * RS + ln;
#pragma unroll
    for (int nt = 0; nt < 4; ++nt) {
      const float* vp = vp0 + 16 * nt;
      union { bf16x8 v; unsigned u[4]; } vf;
#pragma unroll
      for (int e = 0; e < 4; ++e) {
        const int k0 = ((2*e) >> 2 << 4) + d0 + ((2*e) & 3);
        const int k1 = ((2*e+1) >> 2 << 4) + d0 + ((2*e+1) & 3);
        vf.u[e] = cvt2(vp[(size_t)k0 * RS], vp[(size_t)k1 * RS]);
      }
      acc[nt] = __builtin_amdgcn_mfma_f32_16x16x32_bf16(pf.v, vf.v, acc[nt], 0, 0, 0);
    }
  }

  // ---- merge: every wave posts (m,l,acc); wave0 merges A, wave1 merges B ----
  __shared__ float accS[4][16][68];   // stride 68: breaks 16-float power-of-2
  __shared__ float mS[4][16], lS[4][16];

#pragma unroll
  for (int nt = 0; nt < 4; ++nt)
#pragma unroll
    for (int r = 0; r < 4; ++r)
      accS[wv][d0 + r][ln + 16 * nt] = acc[nt][r];
  if (lane < 16) { mS[wv][ln] = m; lS[wv][ln] = lsum; }
  __syncthreads();

  if (wv < 2) {
    const int t   = (wv == 0) ? tileA : tileB;
    const int s0  = (wv == 0) ? 0     : nwA;
    const int s1  = (wv == 0) ? nwA   : 4;
    const int qr0 = t * 16;

    float wgt[4][3], den[4];
#pragma unroll
    for (int r = 0; r < 4; ++r) {
      const int row = d0 + r;
      float Mx = -1e30f;
      for (int s = s0; s < s1; ++s) Mx = fmaxf(Mx, mS[s][row]);
      float dd = 0.f;
#pragma unroll
      for (int ss = 0; ss < 3; ++ss) {
        const int s = s0 + ss;
        float w = 0.f;
        if (s < s1) { w = __expf(mS[s][row] - Mx); dd += lS[s][row] * w; }
        wgt[r][ss] = w;
      }
      den[r] = 1.0f / dd;
    }

#pragma unroll
    for (int nt = 0; nt < 4; ++nt) {
#pragma unroll
      for (int r = 0; r < 4; ++r) {
        float a = 0.f;
#pragma unroll
        for (int ss = 0; ss < 3; ++ss) {
          const int s = s0 + ss;
          if (s < s1) a += accS[s][d0 + r][ln + 16 * nt] * wgt[r][ss];
        }
        Ob[(size_t)(qr0 + d0 + r) * RS + (ln + 16 * nt)] = a * den[r];
      }
    }
  }
}

} // namespace

extern "C" void kernel_launch(void* const* d_in, const int* in_sizes, int n_in,
                              void* d_out, int out_size, void* d_ws, size_t ws_size,
                              hipStream_t stream) {
  const float* Q = (const float*)d_in[0];
  const float* K = (const float*)d_in[1];
  const float* V = (const float*)d_in[2];
  float* O = (float*)d_out;
  (void)in_sizes; (void)n_in; (void)out_size; (void)d_ws; (void)ws_size;

  const int nblocks = (L / 16 / 2) * B * H;   // 64 tile-pairs x 32 (b,h)
  fa_mfma<<<nblocks, 256, 0, stream>>>(Q, K, V, O);
}

// Round 6
// 77.249 us; speedup vs baseline: 2.0721x; 2.0721x over previous
//
#include <hip/hip_runtime.h>
#include <hip/hip_bf16.h>

namespace {

constexpr int B = 4, L = 2048, H = 8, E = 64;
constexpr int RS = H * E;           // 512 floats: row stride in [B,L,H,E]
constexpr float SCALE = 0.125f;     // 1/sqrt(64)
constexpr float THR = 8.0f;         // defer-max threshold (T13)

typedef __attribute__((ext_vector_type(8))) short bf16x8;
typedef __attribute__((ext_vector_type(4))) float f32x4;

__device__ inline unsigned cvt2(float a, float b) {
  __hip_bfloat162 h = __float22bfloat162_rn(make_float2(a, b));  // v_cvt_pk_bf16_f32
  union { __hip_bfloat162 h; unsigned u; } c; c.h = h; return c.u;
}

__device__ inline bf16x8 pack8(float4 a, float4 b) {
  union { bf16x8 v; unsigned u[4]; } r;
  r.u[0] = cvt2(a.x, a.y); r.u[1] = cvt2(a.z, a.w);
  r.u[2] = cvt2(b.x, b.y); r.u[3] = cvt2(b.z, b.w);
  return r.v;
}

// Block = 4 waves on ADJACENT q-tiles (64 rows) of one (b,h); K/V tiles
// (32 keys) staged once per step into LDS (double-buffered, 1 barrier/step).
// K: row-major bf16, 8B-slot XOR swizzle. V: TRANSPOSED (dim-major) bf16,
// XOR swizzle -> conflict-free b64 fragment reads. Swapped S^T = K*Q^T
// keeps softmax lane-local; P feeds PV's A-operand in place.
__global__ __launch_bounds__(256)
void fa_stage(const float* __restrict__ Q, const float* __restrict__ K,
              const float* __restrict__ V, float* __restrict__ O)
{
  const int tid  = (int)threadIdx.x;
  const int lane = tid & 63;
  const int wv   = tid >> 6;
  const int bi   = (int)blockIdx.x;

  // bh in groups of 4 per XCD (L2 locality); CU-mix quadruples over s so
  // each CU's 4 blocks have equal summed work: ns in {2t+2,64-2t,2t+18,48-2t}
  const int bh = (bi & 7) * 4 + ((bi >> 3) & 3);
  const int s  = bi >> 5;                    // 0..31
  const int t_ = s & 7, qd = s >> 3;
  int u;
  if      (qd == 0) u = t_;
  else if (qd == 1) u = 31 - t_;
  else if (qd == 2) u = 8 + t_;
  else              u = 23 - t_;
  const int b = bh >> 3, h = bh & 7;
  const int ns = 2 * u + 2;                  // shared K steps for this block

  const int ln = lane & 15, lg = lane >> 4, d0 = lg * 4;

  const size_t base = (size_t)b * L * RS + (size_t)h * E;
  const float* Qb = Q + base;
  const float* Kb = K + base;
  const float* Vb = V + base;
  float*       Ob = O + base;

  const int qrow0 = u * 64 + wv * 16;        // this wave's q-tile
  const int nsW   = ((qrow0 + 15) >> 5) + 1; // steps this wave needs

  __shared__ __align__(16) unsigned char KT[2][32 * 128]; // [key][dim] bf16, swizzled
  __shared__ __align__(16) unsigned char VT[2][64 * 64];  // [dim][key] bf16, swizzled

  // ---- Q fragments (B-operand: col = q-row qrow0+ln) ----
  const float* qp = Qb + (size_t)(qrow0 + ln) * RS;
  const bf16x8 qf0 = pack8(*(const float4*)(qp + d0),      *(const float4*)(qp + d0 + 16));
  const bf16x8 qf1 = pack8(*(const float4*)(qp + d0 + 32), *(const float4*)(qp + d0 + 48));

  // staging registers (prefetched tile)
  float4 r0, r1, r2, r3;
  const int so = tid & 7;            // dim octet
  const int sk = (tid & 127) >> 3;   // V: keypair 0..15 | K: key 0..15

  auto stage_load = [&](int step) {
    const int kv0 = step * 32;
    if (tid < 128) {                 // V: rows 2sk, 2sk+1, dims so*8..+7
      const float* p = Vb + (size_t)(kv0 + 2 * sk) * RS + so * 8;
      r0 = *(const float4*)(p);      r1 = *(const float4*)(p + 4);
      r2 = *(const float4*)(p + RS); r3 = *(const float4*)(p + RS + 4);
    } else {                         // K: rows sk, sk+16, dims so*8..+7
      const float* p = Kb + (size_t)(kv0 + sk) * RS + so * 8;
      r0 = *(const float4*)(p);           r1 = *(const float4*)(p + 4);
      r2 = *(const float4*)(p + 16 * RS); r3 = *(const float4*)(p + 16 * RS + 4);
    }
  };

  auto stage_write = [&](int buf) {
    if (tid < 128) {                 // V transposed: Vt[dim][key], b32 = key pair
      unsigned char* Vt = VT[buf];
      const float va[8] = {r0.x, r0.y, r0.z, r0.w, r1.x, r1.y, r1.z, r1.w};
      const float vb_[8] = {r2.x, r2.y, r2.z, r2.w, r3.x, r3.y, r3.z, r3.w};
#pragma unroll
      for (int j = 0; j < 8; ++j) {
        const int d = so * 8 + j;
        const int off = d * 64 + ((4 * sk) ^ (8 * (d & 7)) ^ (32 * ((d >> 3) & 1)));
        *(unsigned*)(Vt + off) = cvt2(va[j], vb_[j]);  // low = key 2sk, high = 2sk+1
      }
    } else {                         // K row-major: Kt[key][dim]
      unsigned char* Kt = KT[buf];
      {
        const int swz = 8 * (sk & 7);
        uint2 lo, hi;
        lo.x = cvt2(r0.x, r0.y); lo.y = cvt2(r0.z, r0.w);
        hi.x = cvt2(r1.x, r1.y); hi.y = cvt2(r1.z, r1.w);
        *(uint2*)(Kt + sk * 128 + ((so * 16) ^ swz))     = lo;
        *(uint2*)(Kt + sk * 128 + ((so * 16 + 8) ^ swz)) = hi;
      }
      {
        const int k1 = sk + 16;
        const int swz = 8 * (k1 & 7);
        uint2 lo, hi;
        lo.x = cvt2(r2.x, r2.y); lo.y = cvt2(r2.z, r2.w);
        hi.x = cvt2(r3.x, r3.y); hi.y = cvt2(r3.z, r3.w);
        *(uint2*)(Kt + k1 * 128 + ((so * 16) ^ swz))     = lo;
        *(uint2*)(Kt + k1 * 128 + ((so * 16 + 8) ^ swz)) = hi;
      }
    }
  };

  f32x4 acc[4];
#pragma unroll
  for (int nt = 0; nt < 4; ++nt) acc[nt] = (f32x4){0.f, 0.f, 0.f, 0.f};
  float m = -1e30f, lsum = 0.f;

  const int swzK = 8 * (ln & 7);                       // key&7 == ln&7
  const int swzV = (8 * (ln & 7)) ^ (32 * ((ln >> 3) & 1)); // (d&7)==(ln&7), d bit3==ln bit3

  stage_load(0);
  stage_write(0);
  __syncthreads();

  for (int step = 0; step < ns; ++step) {
    const int buf = step & 1;
    if (step + 1 < ns) stage_load(step + 1);   // T14: issue early

    if (step < nsW) {
      // ---- K fragments from LDS ----
      const unsigned char* Kt = KT[buf];
      union { bf16x8 v; uint2 p[2]; } kf[4];
#pragma unroll
      for (int kb2 = 0; kb2 < 2; ++kb2) {      // key block 0 / 16
        const unsigned char* row = Kt + (kb2 * 16 + ln) * 128;
#pragma unroll
        for (int dh = 0; dh < 2; ++dh) {       // dims 0-31 / 32-63
          kf[kb2 * 2 + dh].p[0] = *(const uint2*)(row + ((lg * 8 + 64 * dh) ^ swzK));
          kf[kb2 * 2 + dh].p[1] = *(const uint2*)(row + ((lg * 8 + 32 + 64 * dh) ^ swzK));
        }
      }

      f32x4 st0 = (f32x4){0.f, 0.f, 0.f, 0.f}, st1 = st0;
      st0 = __builtin_amdgcn_mfma_f32_16x16x32_bf16(kf[0].v, qf0, st0, 0, 0, 0);
      st0 = __builtin_amdgcn_mfma_f32_16x16x32_bf16(kf[1].v, qf1, st0, 0, 0, 0);
      st1 = __builtin_amdgcn_mfma_f32_16x16x32_bf16(kf[2].v, qf0, st1, 0, 0, 0);
      st1 = __builtin_amdgcn_mfma_f32_16x16x32_bf16(kf[3].v, qf1, st1, 0, 0, 0);

      float x[8];
#pragma unroll
      for (int r = 0; r < 4; ++r) { x[r] = SCALE * st0[r]; x[4 + r] = SCALE * st1[r]; }

      if (step == nsW - 1) {                   // only last needed step crosses diag
        const int kv0 = step * 32;
        const int qr = qrow0 + ln;
#pragma unroll
        for (int e = 0; e < 8; ++e) {
          const int key = kv0 + ((e >> 2) << 4) + d0 + (e & 3);
          if (key > qr) x[e] = -1e30f;
        }
      }

      // ---- online softmax with defer-max ----
      float mx = x[0];
#pragma unroll
      for (int e = 1; e < 8; ++e) mx = fmaxf(mx, x[e]);
      mx = fmaxf(mx, __shfl_xor(mx, 16, 64));
      mx = fmaxf(mx, __shfl_xor(mx, 32, 64));

      if (!__all(mx <= m + THR)) {
        const float newm = fmaxf(m, mx);
        const float sc = __expf(m - newm);
        lsum *= sc;
        float scr[4];
#pragma unroll
        for (int r = 0; r < 4; ++r) scr[r] = __shfl(sc, d0 + r, 64);
#pragma unroll
        for (int nt = 0; nt < 4; ++nt) {
          acc[nt][0] *= scr[0]; acc[nt][1] *= scr[1];
          acc[nt][2] *= scr[2]; acc[nt][3] *= scr[3];
        }
        m = newm;
      }

      float p[8]; float ps = 0.f;
#pragma unroll
      for (int e = 0; e < 8; ++e) { p[e] = __expf(x[e] - m); ps += p[e]; }
      ps += __shfl_xor(ps, 16, 64);
      ps += __shfl_xor(ps, 32, 64);
      lsum += ps;

      union { bf16x8 v; unsigned u[4]; } pf;
#pragma unroll
      for (int e = 0; e < 4; ++e) pf.u[e] = cvt2(p[2 * e], p[2 * e + 1]);

      // ---- V fragments from LDS (transposed layout) + PV ----
      const unsigned char* Vt = VT[buf];
#pragma unroll
      for (int nt = 0; nt < 4; ++nt) {
        const unsigned char* row = Vt + (ln + 16 * nt) * 64;
        union { bf16x8 v; uint2 p[2]; } vf;
        vf.p[0] = *(const uint2*)(row + ((lg * 8) ^ swzV));       // keys d0..d0+3
        vf.p[1] = *(const uint2*)(row + ((lg * 8 + 32) ^ swzV));  // keys 16+d0..+3
        acc[nt] = __builtin_amdgcn_mfma_f32_16x16x32_bf16(pf.v, vf.v, acc[nt], 0, 0, 0);
      }
    }

    if (step + 1 < ns) stage_write(buf ^ 1);   // write next tile (other buffer)
    __syncthreads();
  }

  // ---- epilogue: normalize and store ----
  const float il = 1.0f / lsum;
  float inv[4];
#pragma unroll
  for (int r = 0; r < 4; ++r) inv[r] = __shfl(il, d0 + r, 64);
#pragma unroll
  for (int nt = 0; nt < 4; ++nt)
#pragma unroll
    for (int r = 0; r < 4; ++r)
      Ob[(size_t)(qrow0 + d0 + r) * RS + (ln + 16 * nt)] = acc[nt][r] * inv[r];
}

} // namespace

extern "C" void kernel_launch(void* const* d_in, const int* in_sizes, int n_in,
                              void* d_out, int out_size, void* d_ws, size_t ws_size,
                              hipStream_t stream) {
  const float* Q = (const float*)d_in[0];
  const float* K = (const float*)d_in[1];
  const float* V = (const float*)d_in[2];
  float* O = (float*)d_out;
  (void)in_sizes; (void)n_in; (void)out_size; (void)d_ws; (void)ws_size;

  const int nblocks = (L / 64) * B * H;   // 32 q-groups x 32 (b,h) = 1024
  fa_stage<<<nblocks, 256, 0, stream>>>(Q, K, V, O);
}

// Round 7
// 63.694 us; speedup vs baseline: 2.5131x; 1.2128x over previous
//
#include <hip/hip_runtime.h>
#include <hip/hip_bf16.h>

namespace {

constexpr int B_ = 4, L = 2048, H = 8, E = 64;
constexpr int RS = H * E;           // 512 floats: row stride in [B,L,H,E]
constexpr float SCALE = 0.125f;     // 1/sqrt(64)
constexpr float THR = 8.0f;         // defer-max threshold (T13)

// workspace layout (floats): acc[2][32][8][128][64] ++ m[2][32][8][128] ++ l[...]
constexpr size_t ACCF = (size_t)2 * 32 * 8 * 128 * 64;   // 4,194,304
constexpr size_t MOFF = ACCF;
constexpr size_t PART_ROWS = (size_t)32 * 8 * 128;       // 32,768 rows per part
constexpr size_t LOFF = MOFF + 2 * PART_ROWS;
constexpr size_t WS_FLOATS = LOFF + 2 * PART_ROWS;       // 4,325,376 -> 17.3MB

typedef __attribute__((ext_vector_type(8))) short bf16x8;
typedef __attribute__((ext_vector_type(4))) float f32x4;

__device__ inline unsigned cvt2(float a, float b) {
  __hip_bfloat162 hh = __float22bfloat162_rn(make_float2(a, b));  // v_cvt_pk_bf16_f32
  union { __hip_bfloat162 h; unsigned u; } c; c.h = hh; return c.u;
}

__device__ inline bf16x8 pack8(float4 a, float4 b) {
  union { bf16x8 v; unsigned u[4]; } r;
  r.u[0] = cvt2(a.x, a.y); r.u[1] = cvt2(a.z, a.w);
  r.u[2] = cvt2(b.x, b.y); r.u[3] = cvt2(b.z, b.w);
  return r.v;
}

// Block = 8 waves. role 0 (alpha): group g=pp complete (4pp+4 steps) then head
// of v=15-pp (30-4pp steps) -> partial. role 1 (beta): tail 34 steps of v ->
// partial. role 2 (fallback, no ws): g then v complete (68 steps).
// All split-mode blocks have EXACTLY 34 steps -> equal makespan.
// QK^T swapped (S^T = K*Q^T); QK k-slot mapping CONTIGUOUS (slot e <-> dim
// 8*lg+e; permutation-invariant since A and B share it) -> K frag is one
// ds_read_b128. K LDS swizzle: byte ^= 16*(key&7) (b128 floor). V stored
// transposed [dim][key], swizzle byte ^= 8*((dim>>1)&7) (b64 floor).
__global__ __launch_bounds__(512)
void fa_split(const float* __restrict__ Q, const float* __restrict__ K,
              const float* __restrict__ V, float* __restrict__ O,
              float* __restrict__ ws, int splitMode)
{
  const int tid  = (int)threadIdx.x;
  const int lane = tid & 63;
  const int wv   = tid >> 6;
  const int bi   = (int)blockIdx.x;
  const int bh   = bi & 31;                 // low bits -> XCD locality per (b,h)
  const int pp   = (bi >> 5) & 7;
  const int role = splitMode ? (bi >> 8) : 2;
  const int b = bh >> 3, h = bh & 7;
  const int ln = lane & 15, lg = lane >> 4, d0 = lg * 4;
  const int nsg = 4 * pp + 4;

  // schedule
  int total, ph1sb0, qgA, k0A, qgB; bool finA, finB; int part;
  if (role == 0)      { total = 34; ph1sb0 = nsg;  qgA = pp;      k0A = 0;          finA = true;  qgB = 15 - pp; finB = false; part = 0; }
  else if (role == 1) { total = 34; ph1sb0 = 1000; qgA = 15 - pp; k0A = 30 - 4*pp;  finA = false; qgB = 0;       finB = false; part = 1; }
  else                { total = 68; ph1sb0 = nsg;  qgA = pp;      k0A = 0;          finA = true;  qgB = 15 - pp; finB = true;  part = 0; }

  const size_t base = (size_t)b * L * RS + (size_t)h * E;
  const float* Qb = Q + base;
  const float* Kb = K + base;
  const float* Vb = V + base;
  float*       Ob = O + base;

  __shared__ __align__(16) unsigned char KT[2][32 * 128]; // [key][dim] bf16, swz
  __shared__ __align__(16) unsigned char VT[2][64 * 64];  // [dim][key] bf16, swz

  // ---- staging thread roles ----
  const int dd = tid & 31, kq = (tid >> 5) & 7;   // V-stage (tid<256)
  const int kk = (tid - 256) >> 3, dq = tid & 7;  // K-stage (tid>=256)
  float v0,v1,v2,v3,w0,w1,w2,w3;                  // V regs
  float4 f0, f1;                                  // K regs

  auto stage_load = [&](int ks) {
    const int kv0 = ks * 32;
    if (tid < 256) {
      const float* vp = Vb + (size_t)(kv0 + 4 * kq) * RS + dd;
      v0 = vp[0];  v1 = vp[RS];      v2 = vp[2*RS];      v3 = vp[3*RS];
      w0 = vp[32]; w1 = vp[RS + 32]; w2 = vp[2*RS + 32]; w3 = vp[3*RS + 32];
    } else {
      const float* kp = Kb + (size_t)(kv0 + kk) * RS + dq * 4;
      f0 = *(const float4*)kp; f1 = *(const float4*)(kp + 32);
    }
  };
  auto stage_write = [&](int bufI) {
    if (tid < 256) {
      unsigned char* vt = VT[bufI];
      const int off = (8 * kq) ^ (8 * ((dd >> 1) & 7));
      uint2 lo; lo.x = cvt2(v0, v1); lo.y = cvt2(v2, v3);
      *(uint2*)(vt + dd * 64 + off) = lo;               // dim dd, keys 4kq..+3
      uint2 hi; hi.x = cvt2(w0, w1); hi.y = cvt2(w2, w3);
      *(uint2*)(vt + (dd + 32) * 64 + off) = hi;        // dim dd+32 (same swz)
    } else {
      unsigned char* kt = KT[bufI] + kk * 128;
      const int sz = 16 * (kk & 7);
      uint2 a; a.x = cvt2(f0.x, f0.y); a.y = cvt2(f0.z, f0.w);
      *(uint2*)(kt + ((8 * dq) ^ sz)) = a;              // dims 4dq..+3
      uint2 c; c.x = cvt2(f1.x, f1.y); c.y = cvt2(f1.z, f1.w);
      *(uint2*)(kt + ((64 + 8 * dq) ^ sz)) = c;         // dims 32+4dq..+3
    }
  };

  // ---- per-phase state ----
  int qg = qgA; bool curFin = finA;
  int qrow0 = qg * 128 + wv * 16;
  int nsW   = 4 * qg + ((wv * 16 + 47) >> 5);

  bf16x8 qf0, qf1;
  auto load_q = [&]() {
    const float* qp = Qb + (size_t)(qrow0 + ln) * RS + 8 * lg;
    qf0 = pack8(*(const float4*)qp,        *(const float4*)(qp + 4));
    qf1 = pack8(*(const float4*)(qp + 32), *(const float4*)(qp + 36));
  };
  load_q();

  f32x4 acc[4];
#pragma unroll
  for (int nt = 0; nt < 4; ++nt) acc[nt] = (f32x4){0.f, 0.f, 0.f, 0.f};
  float m = -1e30f, lsum = 0.f;

  auto epilogue = [&]() {
    if (curFin) {
      const float il = 1.0f / lsum;
      float inv[4];
#pragma unroll
      for (int r = 0; r < 4; ++r) inv[r] = __shfl(il, d0 + r, 64);
#pragma unroll
      for (int nt = 0; nt < 4; ++nt)
#pragma unroll
        for (int r = 0; r < 4; ++r)
          Ob[(size_t)(qrow0 + d0 + r) * RS + (ln + 16 * nt)] = acc[nt][r] * inv[r];
    } else {
      const int vg = qg - 8;
      const size_t rb = ((size_t)part * 32 + bh) * 1024 + (size_t)vg * 128;
#pragma unroll
      for (int nt = 0; nt < 4; ++nt)
#pragma unroll
        for (int r = 0; r < 4; ++r)
          ws[(rb + wv * 16 + d0 + r) * 64 + ln + 16 * nt] = acc[nt][r];
      if (lane < 16) {
        ws[MOFF + rb + wv * 16 + lane] = m;
        ws[LOFF + rb + wv * 16 + lane] = lsum;
      }
    }
  };

  const int swzK = 16 * (ln & 7);
  const int swzV = 8 * (ln >> 1);

  stage_load(k0A);
  stage_write(0);
  __syncthreads();
  int buf = 0;

  for (int sb = 0; sb < total; ++sb) {
    const bool haveNext = (sb + 1) < total;
    if (haveNext) {
      const int sn = sb + 1;
      stage_load((sn < ph1sb0) ? (k0A + sn) : (sn - ph1sb0));   // T14: issue early
    }
    const int kstep = (sb < ph1sb0) ? (k0A + sb) : (sb - ph1sb0);

    if (kstep < nsW) {
      // ---- K fragments: one b128 each (contiguous k-slots) ----
      const unsigned char* Kt = KT[buf];
      const unsigned char* kr0 = Kt + ln * 128;
      const unsigned char* kr1 = Kt + (16 + ln) * 128;
      const bf16x8 kf0 = *(const bf16x8*)(kr0 + ((16 * lg) ^ swzK));
      const bf16x8 kf1 = *(const bf16x8*)(kr0 + ((64 + 16 * lg) ^ swzK));
      const bf16x8 kf2 = *(const bf16x8*)(kr1 + ((16 * lg) ^ swzK));
      const bf16x8 kf3 = *(const bf16x8*)(kr1 + ((64 + 16 * lg) ^ swzK));

      f32x4 st0 = (f32x4){0.f, 0.f, 0.f, 0.f}, st1 = st0;
      st0 = __builtin_amdgcn_mfma_f32_16x16x32_bf16(kf0, qf0, st0, 0, 0, 0);
      st0 = __builtin_amdgcn_mfma_f32_16x16x32_bf16(kf1, qf1, st0, 0, 0, 0);
      st1 = __builtin_amdgcn_mfma_f32_16x16x32_bf16(kf2, qf0, st1, 0, 0, 0);
      st1 = __builtin_amdgcn_mfma_f32_16x16x32_bf16(kf3, qf1, st1, 0, 0, 0);

      float x[8];
#pragma unroll
      for (int r = 0; r < 4; ++r) { x[r] = SCALE * st0[r]; x[4 + r] = SCALE * st1[r]; }

      if (kstep == nsW - 1) {                 // diagonal tile
        const int kv0 = kstep * 32;
        const int qr = qrow0 + ln;
#pragma unroll
        for (int e = 0; e < 8; ++e) {
          const int key = kv0 + ((e >> 2) << 4) + d0 + (e & 3);
          if (key > qr) x[e] = -1e30f;
        }
      }

      // ---- online softmax with defer-max ----
      float mx = x[0];
#pragma unroll
      for (int e = 1; e < 8; ++e) mx = fmaxf(mx, x[e]);
      mx = fmaxf(mx, __shfl_xor(mx, 16, 64));
      mx = fmaxf(mx, __shfl_xor(mx, 32, 64));

      if (!__all(mx <= m + THR)) {
        const float newm = fmaxf(m, mx);
        const float sc = __expf(m - newm);
        lsum *= sc;
        float scr[4];
#pragma unroll
        for (int r = 0; r < 4; ++r) scr[r] = __shfl(sc, d0 + r, 64);
#pragma unroll
        for (int nt = 0; nt < 4; ++nt) {
          acc[nt][0] *= scr[0]; acc[nt][1] *= scr[1];
          acc[nt][2] *= scr[2]; acc[nt][3] *= scr[3];
        }
        m = newm;
      }

      float p[8]; float ps = 0.f;
#pragma unroll
      for (int e = 0; e < 8; ++e) { p[e] = __expf(x[e] - m); ps += p[e]; }
      ps += __shfl_xor(ps, 16, 64);
      ps += __shfl_xor(ps, 32, 64);
      lsum += ps;

      union { bf16x8 v; unsigned u[4]; } pf;
#pragma unroll
      for (int e = 0; e < 4; ++e) pf.u[e] = cvt2(p[2 * e], p[2 * e + 1]);

      // ---- V fragments (canonical slots) + PV ----
      const unsigned char* Vt = VT[buf];
#pragma unroll
      for (int nt = 0; nt < 4; ++nt) {
        const unsigned char* row = Vt + (ln + 16 * nt) * 64;
        union { bf16x8 v; uint2 p2[2]; } vf;
        vf.p2[0] = *(const uint2*)(row + ((8 * lg) ^ swzV));
        vf.p2[1] = *(const uint2*)(row + ((8 * lg + 32) ^ swzV));
        acc[nt] = __builtin_amdgcn_mfma_f32_16x16x32_bf16(pf.v, vf.v, acc[nt], 0, 0, 0);
      }
    }

    if (sb == ph1sb0 - 1) {                   // phase boundary (block-uniform)
      epilogue();
#pragma unroll
      for (int nt = 0; nt < 4; ++nt) acc[nt] = (f32x4){0.f, 0.f, 0.f, 0.f};
      m = -1e30f; lsum = 0.f;
      qg = qgB; curFin = finB;
      qrow0 = qg * 128 + wv * 16;
      nsW = 4 * qg + ((wv * 16 + 47) >> 5);
      load_q();
    }

    if (haveNext) stage_write(buf ^ 1);
    __syncthreads();
    buf ^= 1;
  }

  epilogue();
}

// Combine the two split-K partials for v-rows (groups 8..15) and normalize.
__global__ __launch_bounds__(256)
void fa_merge(const float* __restrict__ ws, float* __restrict__ O)
{
  const int idx = (int)blockIdx.x * 256 + (int)threadIdx.x;   // 0..524287
  const int d4  = idx & 15;
  const int row = (idx >> 4) & 127;
  const int vg  = (idx >> 11) & 7;
  const int bh  = idx >> 14;
  const size_t rbase = ((size_t)bh * 8 + vg) * 128 + row;

  const float m0 = ws[MOFF + rbase],             l0 = ws[LOFF + rbase];
  const float m1 = ws[MOFF + PART_ROWS + rbase], l1 = ws[LOFF + PART_ROWS + rbase];
  const float M  = fmaxf(m0, m1);
  const float e0 = __expf(m0 - M), e1 = __expf(m1 - M);
  const float inv = 1.0f / (l0 * e0 + l1 * e1);

  const float4 a0 = *(const float4*)(ws + rbase * 64 + 4 * d4);
  const float4 a1 = *(const float4*)(ws + PART_ROWS * 64 + rbase * 64 + 4 * d4);

  const int b = bh >> 3, h = bh & 7;
  const int orow = (8 + vg) * 128 + row;
  float4 o;
  o.x = (a0.x * e0 + a1.x * e1) * inv;
  o.y = (a0.y * e0 + a1.y * e1) * inv;
  o.z = (a0.z * e0 + a1.z * e1) * inv;
  o.w = (a0.w * e0 + a1.w * e1) * inv;
  *(float4*)(O + ((size_t)(b * L + orow) * H + h) * E + 4 * d4) = o;
}

} // namespace

extern "C" void kernel_launch(void* const* d_in, const int* in_sizes, int n_in,
                              void* d_out, int out_size, void* d_ws, size_t ws_size,
                              hipStream_t stream) {
  const float* Q = (const float*)d_in[0];
  const float* K = (const float*)d_in[1];
  const float* V = (const float*)d_in[2];
  float* O = (float*)d_out;
  (void)in_sizes; (void)n_in; (void)out_size;

  const bool split = ws_size >= WS_FLOATS * sizeof(float);
  if (split) {
    fa_split<<<512, 512, 0, stream>>>(Q, K, V, O, (float*)d_ws, 1);
    fa_merge<<<2048, 256, 0, stream>>>((const float*)d_ws, O);
  } else {
    fa_split<<<256, 512, 0, stream>>>(Q, K, V, O, (float*)d_ws, 0);
  }
}

// Round 9
// 56.854 us; speedup vs baseline: 2.8155x; 1.1203x over previous
//
#include <hip/hip_runtime.h>
#include <hip/hip_bf16.h>

namespace {

constexpr int B_ = 4, L = 2048, H = 8, E = 64;
constexpr int RS = H * E;            // 512 floats: row stride in [B,L,H,E]
constexpr float CS = 0.125f * 1.44269504f;  // SCALE * log2(e): exp2-direct
constexpr float THR2 = 11.5f;        // defer-max threshold in log2 units

// workspace layout (floats): acc[2][32][8][128][64] ++ m[2][32][8][128] ++ l[...]
constexpr size_t ACCF = (size_t)2 * 32 * 8 * 128 * 64;
constexpr size_t MOFF = ACCF;
constexpr size_t PART_ROWS = (size_t)32 * 8 * 128;
constexpr size_t LOFF = MOFF + 2 * PART_ROWS;
constexpr size_t WS_FLOATS = LOFF + 2 * PART_ROWS;   // ~17.3 MB

typedef __attribute__((ext_vector_type(8))) short bf16x8;
typedef __attribute__((ext_vector_type(4))) float f32x4;

__device__ inline unsigned cvt2(float a, float b) {
  __hip_bfloat162 hh = __float22bfloat162_rn(make_float2(a, b));  // v_cvt_pk_bf16_f32
  union { __hip_bfloat162 h; unsigned u; } c; c.h = hh; return c.u;
}

// Block = 8 waves, KVBLK=64. Pair (g, 15-g) of 128-row q-groups: step counts
// (2g+2) + (32-2g) = 34 -> two roles of EXACTLY 17 steps (equal makespan).
// role 0: group g complete, then head of v=15-g -> partial(part 0).
// role 1: tail 17 steps of v -> partial(part 1). role 2 (no-ws fallback): 34.
// Swapped S^T = K*Q^T; exp2-domain softmax (scale folded into Q).
// K LDS [key][128B] chunk^= key&7; V LDS [dim][key*2B] chunk^= dim&7.
__global__ __launch_bounds__(512)
void fa_split(const float* __restrict__ Q, const float* __restrict__ K,
              const float* __restrict__ V, float* __restrict__ O,
              float* __restrict__ ws, int splitMode)
{
  const int tid  = (int)threadIdx.x;
  const int lane = tid & 63;
  const int wv   = tid >> 6;
  const int bi   = (int)blockIdx.x;
  const int bh   = bi & 31;                 // low bits -> XCD L2 locality
  const int pp   = (bi >> 5) & 7;
  const int role = splitMode ? (bi >> 8) : 2;
  const int b = bh >> 3, h = bh & 7;
  const int ln = lane & 15, lg = lane >> 4, d0 = lg * 4;

  // schedule (64-key steps)
  int total, ph1sb0, qgA, k0A, qgB; bool finA, finB; int part;
  const int g = pp, v = 15 - pp;
  if (role == 0)      { total = 17; ph1sb0 = 2*g+2; qgA = g; k0A = 0;        finA = true;  qgB = v; finB = false; part = 0; }
  else if (role == 1) { total = 17; ph1sb0 = 1000;  qgA = v; k0A = 15 - 2*g; finA = false; qgB = 0; finB = false; part = 1; }
  else                { total = 34; ph1sb0 = 2*g+2; qgA = g; k0A = 0;        finA = true;  qgB = v; finB = true;  part = 0; }

  const size_t base = (size_t)b * L * RS + (size_t)h * E;
  const float* Qb = Q + base;
  const float* Kb = K + base;
  const float* Vb = V + base;
  float*       Ob = O + base;

  __shared__ __align__(16) unsigned char KT[2][64 * 128]; // [key][dim*2B], swz
  __shared__ __align__(16) unsigned char VT[2][64 * 128]; // [dim][key*2B], swz

  // ---- staging: all 512 threads stage both V and K ----
  const int vdd = tid & 63, vkq = tid >> 6;   // V: dim vdd, keys 8vkq..+7
  const int kky = tid >> 3, kc  = tid & 7;    // K: key kky, dims 8kc..+7
  float vr[8]; float4 kr0, kr1;

  auto stage_load = [&](int ks) {
    const int kv0 = ks * 64;
    const float* vp = Vb + (size_t)(kv0 + 8 * vkq) * RS + vdd;
#pragma unroll
    for (int j = 0; j < 8; ++j) vr[j] = vp[(size_t)j * RS];
    const float* kp = Kb + (size_t)(kv0 + kky) * RS + 8 * kc;
    kr0 = *(const float4*)kp; kr1 = *(const float4*)(kp + 4);
  };
  auto stage_write = [&](int bufI) {
    union { uint4 q; unsigned u[4]; } w;
    w.u[0] = cvt2(vr[0], vr[1]); w.u[1] = cvt2(vr[2], vr[3]);
    w.u[2] = cvt2(vr[4], vr[5]); w.u[3] = cvt2(vr[6], vr[7]);
    *(uint4*)(VT[bufI] + vdd * 128 + 16 * (vkq ^ (vdd & 7))) = w.q;
    union { uint4 q; unsigned u[4]; } y;
    y.u[0] = cvt2(kr0.x, kr0.y); y.u[1] = cvt2(kr0.z, kr0.w);
    y.u[2] = cvt2(kr1.x, kr1.y); y.u[3] = cvt2(kr1.z, kr1.w);
    *(uint4*)(KT[bufI] + kky * 128 + 16 * (kc ^ (kky & 7))) = y.q;
  };

  // ---- per-phase state ----
  int qg = qgA; bool curFin = finA;
  int qrow0 = qg * 128 + wv * 16;
  int nsW   = (qrow0 + 79) >> 6;             // 64-key steps this wave needs

  bf16x8 qf0, qf1;
  auto load_q = [&]() {                      // Q pre-scaled by CS (exp2 domain)
    const float* qp = Qb + (size_t)(qrow0 + ln) * RS + 8 * lg;
    float4 a = *(const float4*)qp,        c = *(const float4*)(qp + 4);
    float4 d = *(const float4*)(qp + 32), e = *(const float4*)(qp + 36);
    union { bf16x8 v8; unsigned u[4]; } r0, r1;
    r0.u[0] = cvt2(a.x * CS, a.y * CS); r0.u[1] = cvt2(a.z * CS, a.w * CS);
    r0.u[2] = cvt2(c.x * CS, c.y * CS); r0.u[3] = cvt2(c.z * CS, c.w * CS);
    r1.u[0] = cvt2(d.x * CS, d.y * CS); r1.u[1] = cvt2(d.z * CS, d.w * CS);
    r1.u[2] = cvt2(e.x * CS, e.y * CS); r1.u[3] = cvt2(e.z * CS, e.w * CS);
    qf0 = r0.v8; qf1 = r1.v8;
  };
  load_q();

  f32x4 acc[4];
#pragma unroll
  for (int nt = 0; nt < 4; ++nt) acc[nt] = (f32x4){0.f, 0.f, 0.f, 0.f};
  float m = -1e30f, lsum = 0.f;

  auto epilogue = [&]() {
    if (curFin) {
      const float il = 1.0f / lsum;
      float inv[4];
#pragma unroll
      for (int r = 0; r < 4; ++r) inv[r] = __shfl(il, d0 + r, 64);
#pragma unroll
      for (int nt = 0; nt < 4; ++nt)
#pragma unroll
        for (int r = 0; r < 4; ++r)
          Ob[(size_t)(qrow0 + d0 + r) * RS + (ln + 16 * nt)] = acc[nt][r] * inv[r];
    } else {
      const int vg = qg - 8;
      const size_t rb = ((size_t)part * 32 + bh) * 1024 + (size_t)vg * 128;
#pragma unroll
      for (int nt = 0; nt < 4; ++nt)
#pragma unroll
        for (int r = 0; r < 4; ++r)
          ws[(rb + wv * 16 + d0 + r) * 64 + ln + 16 * nt] = acc[nt][r];
      if (lane < 16) {
        ws[MOFF + rb + wv * 16 + lane] = m;
        ws[LOFF + rb + wv * 16 + lane] = lsum;
      }
    }
  };

  stage_load(k0A);
  stage_write(0);
  __syncthreads();
  int buf = 0;

  for (int sb = 0; sb < total; ++sb) {
    const bool haveNext = (sb + 1) < total;
    if (haveNext) {
      const int sn = sb + 1;
      stage_load((sn < ph1sb0) ? (k0A + sn) : (sn - ph1sb0));   // T14: issue early
    }
    const int kstep = (sb < ph1sb0) ? (k0A + sb) : (sb - ph1sb0);

    if (kstep < nsW) {
      const unsigned char* Kt = KT[buf];
      const int swzr = 16 * (ln & 7);        // (16kt+ln)&7 == ln&7

      // ---- QK^T: 4 key-tiles x 2 dim-halves ----
      f32x4 st[4];
#pragma unroll
      for (int kt = 0; kt < 4; ++kt) {
        const unsigned char* kr = Kt + (16 * kt + ln) * 128;
        const bf16x8 kfa = *(const bf16x8*)(kr + ((16 * lg) ^ swzr));
        const bf16x8 kfb = *(const bf16x8*)(kr + ((16 * lg + 64) ^ swzr));
        f32x4 s = (f32x4){0.f, 0.f, 0.f, 0.f};
        s = __builtin_amdgcn_mfma_f32_16x16x32_bf16(kfa, qf0, s, 0, 0, 0);
        s = __builtin_amdgcn_mfma_f32_16x16x32_bf16(kfb, qf1, s, 0, 0, 0);
        st[kt] = s;
      }

      float x[16];
#pragma unroll
      for (int kt = 0; kt < 4; ++kt)
#pragma unroll
        for (int r = 0; r < 4; ++r) x[4 * kt + r] = st[kt][r];

      if (kstep == nsW - 1) {                // diagonal tile
        const int kv0 = kstep * 64;
        const int qr = qrow0 + ln;
#pragma unroll
        for (int kt = 0; kt < 4; ++kt)
#pragma unroll
          for (int r = 0; r < 4; ++r) {
            const int key = kv0 + 16 * kt + d0 + r;
            if (key > qr) x[4 * kt + r] = -1e30f;
          }
      }

      // ---- online softmax (exp2 domain) with defer-max ----
      float mx = x[0];
#pragma unroll
      for (int e = 1; e < 16; ++e) mx = fmaxf(mx, x[e]);
      mx = fmaxf(mx, __shfl_xor(mx, 16, 64));
      mx = fmaxf(mx, __shfl_xor(mx, 32, 64));

      if (!__all(mx <= m + THR2)) {
        const float newm = fmaxf(m, mx);
        const float sc = __builtin_exp2f(m - newm);
        lsum *= sc;
        float scr[4];
#pragma unroll
        for (int r = 0; r < 4; ++r) scr[r] = __shfl(sc, d0 + r, 64);
#pragma unroll
        for (int nt = 0; nt < 4; ++nt) {
          acc[nt][0] *= scr[0]; acc[nt][1] *= scr[1];
          acc[nt][2] *= scr[2]; acc[nt][3] *= scr[3];
        }
        m = newm;
      }

      float p[16]; float ps = 0.f;
#pragma unroll
      for (int e = 0; e < 16; ++e) { p[e] = __builtin_exp2f(x[e] - m); ps += p[e]; }
      ps += __shfl_xor(ps, 16, 64);
      ps += __shfl_xor(ps, 32, 64);
      lsum += ps;

      // ---- PV: 2 key-groups x 4 dim-tiles ----
      const unsigned char* Vt = VT[buf];
#pragma unroll
      for (int kg = 0; kg < 2; ++kg) {
        union { bf16x8 v8; unsigned u[4]; } pf;
#pragma unroll
        for (int j = 0; j < 4; ++j)
          pf.u[j] = cvt2(p[8 * kg + 2 * j], p[8 * kg + 2 * j + 1]);
#pragma unroll
        for (int nt = 0; nt < 4; ++nt) {
          const int row = ln + 16 * nt;
          const unsigned char* vrow = Vt + row * 128;
          const int sz = 16 * (row & 7);
          union { bf16x8 v8; uint2 p2[2]; } vf;
          vf.p2[0] = *(const uint2*)(vrow + ((8 * lg + 64 * kg) ^ sz));
          vf.p2[1] = *(const uint2*)(vrow + ((8 * lg + 32 + 64 * kg) ^ sz));
          acc[nt] = __builtin_amdgcn_mfma_f32_16x16x32_bf16(pf.v8, vf.v8, acc[nt], 0, 0, 0);
        }
      }
    }

    if (sb == ph1sb0 - 1) {                  // phase boundary (block-uniform)
      epilogue();
#pragma unroll
      for (int nt = 0; nt < 4; ++nt) acc[nt] = (f32x4){0.f, 0.f, 0.f, 0.f};
      m = -1e30f; lsum = 0.f;
      qg = qgB; curFin = finB;
      qrow0 = qg * 128 + wv * 16;
      nsW = (qrow0 + 79) >> 6;
      load_q();
    }

    if (haveNext) stage_write(buf ^ 1);
    __syncthreads();
    buf ^= 1;
  }

  epilogue();
}

// Combine the two split-K partials for v-rows (groups 8..15); m is log2-domain.
__global__ __launch_bounds__(256)
void fa_merge(const float* __restrict__ ws, float* __restrict__ O)
{
  const int idx = (int)blockIdx.x * 256 + (int)threadIdx.x;   // 0..524287
  const int d4  = idx & 15;
  const int row = (idx >> 4) & 127;
  const int vg  = (idx >> 11) & 7;
  const int bh  = idx >> 14;
  const size_t rbase = ((size_t)bh * 8 + vg) * 128 + row;

  const float m0 = ws[MOFF + rbase],             l0 = ws[LOFF + rbase];
  const float m1 = ws[MOFF + PART_ROWS + rbase], l1 = ws[LOFF + PART_ROWS + rbase];
  const float M  = fmaxf(m0, m1);
  const float e0 = __builtin_exp2f(m0 - M), e1 = __builtin_exp2f(m1 - M);
  const float inv = 1.0f / (l0 * e0 + l1 * e1);

  const float4 a0 = *(const float4*)(ws + rbase * 64 + 4 * d4);
  const float4 a1 = *(const float4*)(ws + PART_ROWS * 64 + rbase * 64 + 4 * d4);

  const int b = bh >> 3, h = bh & 7;
  const int orow = (8 + vg) * 128 + row;
  float4 o;
  o.x = (a0.x * e0 + a1.x * e1) * inv;
  o.y = (a0.y * e0 + a1.y * e1) * inv;
  o.z = (a0.z * e0 + a1.z * e1) * inv;
  o.w = (a0.w * e0 + a1.w * e1) * inv;
  *(float4*)(O + ((size_t)(b * L + orow) * H + h) * E + 4 * d4) = o;
}

} // namespace

extern "C" void kernel_launch(void* const* d_in, const int* in_sizes, int n_in,
                              void* d_out, int out_size, void* d_ws, size_t ws_size,
                              hipStream_t stream) {
  const float* Q = (const float*)d_in[0];
  const float* K = (const float*)d_in[1];
  const float* V = (const float*)d_in[2];
  float* O = (float*)d_out;
  (void)in_sizes; (void)n_in; (void)out_size;

  const bool split = ws_size >= WS_FLOATS * sizeof(float);
  if (split) {
    fa_split<<<512, 512, 0, stream>>>(Q, K, V, O, (float*)d_ws, 1);
    fa_merge<<<2048, 256, 0, stream>>>((const float*)d_ws, O);
  } else {
    fa_split<<<256, 512, 0, stream>>>(Q, K, V, O, (float*)d_ws, 0);
  }
}